// Round 1
// baseline (229.257 us; speedup 1.0000x reference)
//
#include <hip/hip_runtime.h>
#include <math.h>

#define BB 4
#define CC 32
#define HWSZ (512*512)
#define NMAX 128              // max instances supported (actual N=100 at runtime)
#define NP 132                // padded LDS stride (>= NMAX) for [c][n] float arrays
#define NP64 133              // padded LDS stride (>= NMAX) for u64 pair-sums
#define SS (NMAX * CC)        // 4096: per-batch stride for sums/means

#define PPB 1024              // pixels per block (both big kernels) — was 2048
#define CHUNKS (HWSZ / PPB)   // 256 chunks per batch
#define NBLK (BB * CHUNKS)    // 1024 blocks -> 4 blocks/CU (was 2)

#define DSLICE 8              // dist-term slice blocks per batch (inside k_var)

#define DELTA_VAR_C 0.75f
#define DELTA_DIST_C 2.0f
#define GAMMA_C 0.001f
#define FXS 1048576.0f        // fixed-point scale 2^20
#define FXI (1.0f / 1048576.0f)
#define BIAS 16777216         // 2^24: per-add bias keeping u64 halves non-negative

#define LD4(p) (*(const float4*)(p))

// block reduce over 256 threads (4 waves of 64); result valid on tid==0
__device__ __forceinline__ float block_reduce_256(float v, float* red, int tid) {
    #pragma unroll
    for (int o = 32; o > 0; o >>= 1) v += __shfl_down(v, o, 64);
    if ((tid & 63) == 0) red[tid >> 6] = v;
    __syncthreads();
    if (tid == 0) v = red[0] + red[1] + red[2] + red[3];
    return v;
}

// ---- Kernel 1: per-(batch,instance) sums + counts; packed u64 LDS atomics ----
__global__ __launch_bounds__(256) void k_seg_sum(
    const float* __restrict__ in, const int* __restrict__ lbl,
    const int* __restrict__ n_ptr, int* __restrict__ sums_i,
    unsigned int* __restrict__ counts_u)
{
    const int N = *n_ptr;
    __shared__ unsigned long long s_sum[(CC / 2) * NP64];  // [c/2][n], lo=c, hi=c+1
    __shared__ unsigned int s_cnt[NMAX];
    const int tid = threadIdx.x;

    for (int i = tid; i < (CC / 2) * NP64; i += 256) s_sum[i] = 0ull;
    for (int i = tid; i < NMAX; i += 256) s_cnt[i] = 0u;
    __syncthreads();

    const int b = blockIdx.x / CHUNKS;
    const int p0 = (blockIdx.x % CHUNKS) * PPB;

    const int* lb = lbl + (size_t)b * HWSZ + p0 + tid * 4;
    int4 l4 = *(const int4*)(lb);
    int lab[4] = {l4.x, l4.y, l4.z, l4.w};

    #pragma unroll
    for (int i = 0; i < 4; i++) atomicAdd(&s_cnt[lab[i]], 1u);

    const float* p = in + (size_t)b * CC * HWSZ + p0 + (size_t)tid * 4;

    // channel pair (c, c+1) per iteration; 2-deep prefetch = 4 float4 in flight
    float4 c0a = LD4(p);
    float4 c0b = LD4(p + HWSZ);
    float4 c1a = LD4(p + 2 * (size_t)HWSZ);
    float4 c1b = LD4(p + 3 * (size_t)HWSZ);

    #pragma unroll
    for (int c = 0; c < CC; c += 2) {
        float4 va = c0a, vb = c0b;
        c0a = c1a; c0b = c1b;
        if (c + 4 < CC) {
            const float* q = p + (size_t)(c + 4) * HWSZ;
            c1a = LD4(q);
            c1b = LD4(q + HWSZ);
        }
        float v0[4] = {va.x, va.y, va.z, va.w};
        float v1[4] = {vb.x, vb.y, vb.z, vb.w};
        unsigned long long* row = &s_sum[(c >> 1) * NP64];
        #pragma unroll
        for (int i = 0; i < 4; i++) {
            // truncating cvt (unbiased for symmetric data); bias keeps halves >= 0
            unsigned int lo = (unsigned int)((int)(v0[i] * FXS) + BIAS);
            unsigned int hi = (unsigned int)((int)(v1[i] * FXS) + BIAS);
            unsigned long long pk = (unsigned long long)lo |
                                    ((unsigned long long)hi << 32);
            atomicAdd(&row[lab[i]], pk);
        }
    }
    __syncthreads();

    // flush: unbias with per-label count, global int atomics (L2-pipelined)
    for (int i = tid; i < N * CC; i += 256) {
        int n = i / CC, c = i % CC;
        unsigned long long v = s_sum[(c >> 1) * NP64 + n];
        unsigned int half = (c & 1) ? (unsigned int)(v >> 32) : (unsigned int)v;
        long long val = (long long)half - ((long long)s_cnt[n] << 24);
        if (val != 0)
            atomicAdd(&sums_i[(size_t)b * SS + i], (int)val);
    }
    for (int i = tid; i < N; i += 256) {
        unsigned int cv = s_cnt[i];
        if (cv) atomicAdd(&counts_u[b * NMAX + i], cv);
    }
}

// ---- Kernel 2: means (from sums) + variance hinge + dist + reg, all fused ----
__global__ __launch_bounds__(256) void k_var(
    const float* __restrict__ in, const int* __restrict__ lbl,
    const int* __restrict__ n_ptr, const int* __restrict__ sums_i,
    const unsigned int* __restrict__ counts_u, int* __restrict__ out_acc)
{
    const int N = *n_ptr;
    __shared__ float m_t[CC * NP];   // [c][n] transposed means
    __shared__ float s_invc[NMAX];
    __shared__ float red[4];
    const int tid = threadIdx.x;

    const int b = blockIdx.x / CHUNKS;
    const int chunk = blockIdx.x % CHUNKS;
    const int p0 = chunk * PPB;

    for (int i = tid; i < N; i += 256)
        s_invc[i] = 1.0f / (float)counts_u[b * NMAX + i];
    __syncthreads();
    for (int i = tid; i < N * CC; i += 256) {
        int n = i / CC, c = i % CC;
        m_t[c * NP + n] = (float)sums_i[(size_t)b * SS + i] * FXI * s_invc[n];
    }
    __syncthreads();

    const int* lb = lbl + (size_t)b * HWSZ + p0 + tid * 4;
    int4 l4 = *(const int4*)(lb);
    int lab[4] = {l4.x, l4.y, l4.z, l4.w};
    float acc[4] = {0.f, 0.f, 0.f, 0.f};

    const float* p = in + (size_t)b * CC * HWSZ + p0 + (size_t)tid * 4;
    float4 c0a = LD4(p);
    float4 c0b = LD4(p + HWSZ);
    float4 c1a = LD4(p + 2 * (size_t)HWSZ);
    float4 c1b = LD4(p + 3 * (size_t)HWSZ);

    #pragma unroll
    for (int c = 0; c < CC; c += 2) {
        float4 va = c0a, vb = c0b;
        c0a = c1a; c0b = c1b;
        if (c + 4 < CC) {
            const float* q = p + (size_t)(c + 4) * HWSZ;
            c1a = LD4(q);
            c1b = LD4(q + HWSZ);
        }
        float v0[4] = {va.x, va.y, va.z, va.w};
        #pragma unroll
        for (int i = 0; i < 4; i++) {
            float d = v0[i] - m_t[c * NP + lab[i]];
            acc[i] += d * d;
        }
        float v1[4] = {vb.x, vb.y, vb.z, vb.w};
        #pragma unroll
        for (int i = 0; i < 4; i++) {
            float d = v1[i] - m_t[(c + 1) * NP + lab[i]];
            acc[i] += d * d;
        }
    }

    float vsum = 0.f;
    #pragma unroll
    for (int i = 0; i < 4; i++) {
        float nm = sqrtf(acc[i]);
        float t = fmaxf(nm - DELTA_VAR_C, 0.f);
        vsum += t * t * s_invc[lab[i]];
    }
    float total = vsum * (1.0f / ((float)N * (float)BB));

    // fold pairwise-distance + regularization terms into first DSLICE blocks/batch
    if (chunk < DSLICE) {
        float dist_sum = 0.f;
        for (int pr = chunk * 256 + tid; pr < N * N; pr += DSLICE * 256) {
            int i = pr / N, j = pr - i * N;
            if (i == j) continue;
            float d2 = 0.f;
            #pragma unroll
            for (int c = 0; c < CC; c++) {
                float d = m_t[c * NP + i] - m_t[c * NP + j];
                d2 += d * d;
            }
            float dm = (d2 > 0.f) ? sqrtf(d2) : 1.0f;   // match jnp.where(d2>0,d2,1)
            float h = fmaxf(2.0f * DELTA_DIST_C - dm, 0.f);
            dist_sum += h * h;
        }
        total += dist_sum * (1.0f / ((float)N * (float)(N - 1) * (float)BB));
        if (chunk == 0) {
            float reg_sum = 0.f;
            for (int n = tid; n < N; n += 256) {
                float s = 0.f;
                #pragma unroll
                for (int c = 0; c < CC; c++) { float v = m_t[c * NP + n]; s += v * v; }
                reg_sum += sqrtf(s);
            }
            total += reg_sum * (GAMMA_C / ((float)N * (float)BB));
        }
    }

    float tot = block_reduce_256(total, red, tid);
    if (tid == 0)
        atomicAdd(out_acc, (int)rintf(tot * FXS));
}

// ---- Kernel 3: fixed-point -> float output ----
__global__ void k_final(const int* __restrict__ out_acc, float* __restrict__ out) {
    if (threadIdx.x == 0 && blockIdx.x == 0)
        *out = (float)(*out_acc) * FXI;
}

extern "C" void kernel_launch(void* const* d_in, const int* in_sizes, int n_in,
                              void* d_out, int out_size, void* d_ws, size_t ws_size,
                              hipStream_t stream) {
    (void)in_sizes; (void)n_in; (void)out_size; (void)ws_size;
    const float* in  = (const float*)d_in[0];
    const int*   lbl = (const int*)d_in[1];
    const int*   n_ptr = (const int*)d_in[2];
    float* out = (float*)d_out;

    int* sums_i = (int*)d_ws;                                          // BB*SS
    unsigned int* counts_u = (unsigned int*)(sums_i + BB * SS);        // BB*NMAX
    int* out_acc = (int*)(counts_u + BB * NMAX);                       // 1

    hipMemsetAsync(d_ws, 0, (size_t)(BB * SS + BB * NMAX + 1) * sizeof(int), stream);

    k_seg_sum<<<NBLK, 256, 0, stream>>>(in, lbl, n_ptr, sums_i, counts_u);
    k_var<<<NBLK, 256, 0, stream>>>(in, lbl, n_ptr, sums_i, counts_u, out_acc);
    k_final<<<1, 64, 0, stream>>>(out_acc, out);
}